// Round 6
// baseline (158.753 us; speedup 1.0000x reference)
//
#include <hip/hip_runtime.h>
#include <hip/hip_bf16.h>
#include <stdint.h>

#define BATCH 4096
#define KGRP  8
#define BLK   1024
#define TOTAL 8192

typedef __attribute__((ext_vector_type(8))) short short8;
typedef __attribute__((ext_vector_type(4))) float f32x4;

#define AS1 __attribute__((address_space(1)))
#define AS3 __attribute__((address_space(3)))

// ---------- helpers ----------

__device__ __forceinline__ unsigned short f2bf(float f) {
    union { float f; uint32_t u; } c; c.f = f;
    uint32_t u = c.u;
    u += 0x7fffu + ((u >> 16) & 1u);   // round-to-nearest-even
    return (unsigned short)(u >> 16);
}

__device__ __forceinline__ float fast_tanh(float x) {
    float e = __expf(2.0f * x);
    return 1.0f - 2.0f / (e + 1.0f);
}

// ---------- pass 1 (merged): tanh(v) -> bf16 H, W -> bf16 Wb ----------

__global__ void k_prep(const float4* __restrict__ v, ushort4* __restrict__ H,
                       const float4* __restrict__ W, ushort4* __restrict__ Wb) {
    const int b = blockIdx.x;
    if (b < 2048) {
        const int n4 = BATCH * TOTAL / 4;
        for (int i = b * 256 + threadIdx.x; i < n4; i += 2048 * 256) {
            float4 f = v[i];
            ushort4 o;
            o.x = f2bf(fast_tanh(f.x)); o.y = f2bf(fast_tanh(f.y));
            o.z = f2bf(fast_tanh(f.z)); o.w = f2bf(fast_tanh(f.w));
            H[i] = o;
        }
    } else {
        const int n4 = KGRP * BLK * BLK / 4;
        for (int i = (b - 2048) * 256 + threadIdx.x; i < n4; i += 512 * 256) {
            float4 f = W[i];
            ushort4 o;
            o.x = f2bf(f.x); o.y = f2bf(f.y); o.z = f2bf(f.z); o.w = f2bf(f.w);
            Wb[i] = o;
        }
    }
}

// ---------- pass 2: grouped GEMM, 256x256 tile, BK=32, 16 waves, 2-phase ----------
// C[m][n] = sum_k H[m][k] * W[n][k]; epilogue fuses x + bias (LDS-transposed, float4).
//
// 16 waves (1024 thr) = 4 waves/SIMD: intra-phase latency hiding (the fix for
// rounds 2-5's invariant ~112us at 2 waves/SIMD).
// LDS: 2 bufs x (A[256][32] + B[256][32]) bf16 = 64 KiB + 68 KiB epilogue bounce.
// Swizzle for 64B rows (both-sides, rule #21): phys = log ^ (((log>>7)&3)<<4);
// quarter-wave (16 lanes, rows r..r+15, fixed 16B slot) spreads over all 8
// 16B-positions, 2 lanes each = 2-way = free (m136).
// Staging: 2 gload_lds per wave per tile. A(T+1)->buf^1 at ph0(T) (that A region
// free since boundary(T-1)); B(T+2)->cur at ph1(T) (cur's B region read at ph0(T),
// ph-end barrier separates). One barrier per phase; stage issues sit in the phase
// AFTER the region's last reader phase, so the intervening barrier (+ lgkm-retire
// of reads before their MFMAs) guarantees write-after-read safety.
// Counted wait, one per tile at boundary: guard A(T+1)[ph0(T)] + B(T+1)[ph1(T-1)];
// newer outstanding = B(T+2) -> vmcnt(1). Tail peeled exactly (r3 lesson):
// kt=30: no B-stage -> vmcnt(0); kt=31: no stage, no wait.

__device__ __forceinline__ void gload16(const unsigned short* src, char* dst) {
    __builtin_amdgcn_global_load_lds((const AS1 uint32_t*)src, (AS3 uint32_t*)dst, 16, 0, 0);
}

template<int N> __device__ __forceinline__ void waitvm() {
    if constexpr (N == 0)      asm volatile("s_waitcnt vmcnt(0)" ::: "memory");
    else if constexpr (N == 1) asm volatile("s_waitcnt vmcnt(1)" ::: "memory");
    else if constexpr (N == 2) asm volatile("s_waitcnt vmcnt(2)" ::: "memory");
}

template<bool SA, bool SB, int W>
__device__ __forceinline__ void tile_body(int kt, char* ldsp,
                                          uint32_t aRowB, uint32_t bRowB, uint32_t kc,
                                          f32x4 (*acc)[4],
                                          const unsigned short* Asrc, const unsigned short* Bsrc,
                                          uint32_t sdst) {
    const uint32_t bufb = (uint32_t)(kt & 1) * 32768u;
    const uint32_t nbuf = bufb ^ 32768u;
    const char* Lb = ldsp + bufb;

    short8 bfr[4], am[2];

    // ---- ph0: read B all + A m0,m1; stage A(kt+1) -> other buffer ----
#pragma unroll
    for (int n = 0; n < 4; ++n)
        bfr[n] = *(const short8*)(Lb + bRowB + n * 1024 + kc);
#pragma unroll
    for (int i = 0; i < 2; ++i)
        am[i] = *(const short8*)(Lb + aRowB + i * 1024 + kc);
    if constexpr (SA) gload16(Asrc + (kt + 1) * 32, ldsp + nbuf + sdst);
#pragma unroll
    for (int i = 0; i < 2; ++i)
#pragma unroll
        for (int n = 0; n < 4; ++n)
            acc[i][n] = __builtin_amdgcn_mfma_f32_16x16x32_bf16(am[i], bfr[n], acc[i][n], 0, 0, 0);
    __builtin_amdgcn_s_barrier();
    __builtin_amdgcn_sched_barrier(0);

    // ---- ph1: read A m2,m3; stage B(kt+2) -> own buffer (B region consumed ph0) ----
#pragma unroll
    for (int i = 0; i < 2; ++i)
        am[i] = *(const short8*)(Lb + aRowB + (2 + i) * 1024 + kc);
    if constexpr (SB) gload16(Bsrc + (kt + 2) * 32, ldsp + bufb + 16384u + sdst);
#pragma unroll
    for (int i = 0; i < 2; ++i)
#pragma unroll
        for (int n = 0; n < 4; ++n)
            acc[2 + i][n] = __builtin_amdgcn_mfma_f32_16x16x32_bf16(am[i], bfr[n], acc[2 + i][n], 0, 0, 0);
    if constexpr (W >= 0) {
        waitvm<W>();
        __builtin_amdgcn_s_barrier();
        __builtin_amdgcn_sched_barrier(0);
    }
}

__global__ __launch_bounds__(1024, 4)
void k_gemm(const unsigned short* __restrict__ H, const unsigned short* __restrict__ Wb,
            const float* __restrict__ x, const float* __restrict__ bias,
            float* __restrict__ out) {
    __shared__ __attribute__((aligned(1024))) char lds[135168];   // 64K bufs + 69632 bounce
    char* ldsp = lds;

    // T1: XCD swizzle. bid&7 == XCD; each XCD owns one group -> Wb[g] (2MB) L2-resident.
    const int bid   = blockIdx.x;              // 0..511
    const int g     = bid & 7;
    const int slot  = bid >> 3;                // 0..63
    const int mtile = slot >> 2;               // 0..15
    const int ntile = slot & 3;                // 0..3

    const int tid  = threadIdx.x;
    const int lane = tid & 63;
    const int w    = tid >> 6;                 // 0..15
    const int wr   = w >> 2;                   // 0..3  (M)
    const int wc   = w & 3;                    // 0..3  (N)

    // ds_read swizzled column: logical slot lane>>4, row lane&15
    const uint32_t kc    = ((uint32_t)((lane >> 4) ^ ((lane >> 1) & 3))) << 4;
    const uint32_t aRowB = (uint32_t)(wr * 64 + (lane & 15)) * 64u;             // A @0
    const uint32_t bRowB = 16384u + (uint32_t)(wc * 64 + (lane & 15)) * 64u;    // B @16K

    // staging source pre-swizzle: wave w covers tile rows w*16 + (lane>>2);
    // phys slot lane&3 holds logical slot (lane&3)^((row>>1)&3) = (lane&3)^((lane>>3)&3)
    const int sCol = ((lane & 3) ^ ((lane >> 3) & 3)) << 3;
    const unsigned short* Asrc = H + (size_t)(mtile * 256 + w * 16 + (lane >> 2)) * TOTAL
                                   + (size_t)g * BLK + sCol;
    const unsigned short* Bsrc = Wb + (size_t)g * BLK * BLK
                                    + (size_t)(ntile * 256 + w * 16 + (lane >> 2)) * BLK + sCol;
    const uint32_t sdst = (uint32_t)(w << 10);     // wave-uniform; HW adds lane*16

    f32x4 acc[4][4];
#pragma unroll
    for (int m = 0; m < 4; ++m)
#pragma unroll
        for (int n = 0; n < 4; ++n) acc[m][n] = (f32x4){0.f, 0.f, 0.f, 0.f};

    // prologue: A(0),B(0) -> buf0; A(1),B(1) -> buf1. Guard first two: vmcnt(2).
    gload16(Asrc + 0 * 32, ldsp + 0u + sdst);
    gload16(Bsrc + 0 * 32, ldsp + 16384u + sdst);
    gload16(Asrc + 1 * 32, ldsp + 32768u + sdst);
    gload16(Bsrc + 1 * 32, ldsp + 32768u + 16384u + sdst);
    waitvm<2>();
    __builtin_amdgcn_s_barrier();
    __builtin_amdgcn_sched_barrier(0);

    // kt=0: A(1) already prologue-staged -> SA off; B(2) on; boundary vmcnt(1)
    tile_body<false, true, 1>(0, ldsp, aRowB, bRowB, kc, acc, Asrc, Bsrc, sdst);
#pragma unroll 1
    for (int kt = 1; kt < 30; ++kt)
        tile_body<true, true, 1>(kt, ldsp, aRowB, bRowB, kc, acc, Asrc, Bsrc, sdst);
    tile_body<true, false, 0>(30, ldsp, aRowB, bRowB, kc, acc, Asrc, Bsrc, sdst);
    tile_body<false, false, -1>(31, ldsp, aRowB, bRowB, kc, acc, Asrc, Bsrc, sdst);

    // ---------------- epilogue: out = x + bias + acc, vectorized via LDS bounce ----
    // acc layout (m89/m91): col = lane&15, row = (lane>>4)*4 + j.
    // Per-wave private 16x64 f32 slice, 272B row pitch (68 f32) -> 2-way banks max.
    const int gout = (g + 1) & 7;
    const int q    = lane >> 4;                 // 0..3
    const int cl   = lane & 15;                 // 0..15
    const int row0 = mtile * 256 + wr * 64;
    const int col0 = ntile * 256 + wc * 64;     // within group
    char* eb = ldsp + 65536u + (uint32_t)w * 4352u;
    const float4 bias4 = *(const float4*)&bias[g * BLK + col0 + cl * 4];

#pragma unroll
    for (int m = 0; m < 4; ++m) {
        // scatter this m-block (16 rows x 64 cols) into the slice
#pragma unroll
        for (int n = 0; n < 4; ++n)
#pragma unroll
            for (int j = 0; j < 4; ++j)
                *(float*)(eb + (q * 4 + j) * 272 + (n * 16 + cl) * 4) = acc[m][n][j];
        asm volatile("s_waitcnt lgkmcnt(0)" ::: "memory");   // writes land before reads (and compiler fence)
        __builtin_amdgcn_sched_barrier(0);
        // gather row-major: row = q + 4i, cols cl*4..cl*4+3 -> coalesced float4
#pragma unroll
        for (int i = 0; i < 4; ++i) {
            f32x4 vv = *(const f32x4*)(eb + (q + 4 * i) * 272 + cl * 16);
            const int r = row0 + m * 16 + q + 4 * i;
            const size_t idx = (size_t)r * TOTAL + (size_t)gout * BLK + col0 + cl * 4;
            const float4 xv = *(const float4*)&x[idx];
            float4 o;
            o.x = xv.x + bias4.x + vv[0];
            o.y = xv.y + bias4.y + vv[1];
            o.z = xv.z + bias4.z + vv[2];
            o.w = xv.w + bias4.w + vv[3];
            *(float4*)&out[idx] = o;
        }
        asm volatile("s_waitcnt lgkmcnt(0)" ::: "memory");   // reads done before next m overwrites
        __builtin_amdgcn_sched_barrier(0);
    }
}

// ---------- fallback (ws too small): correct but slow ----------

__global__ void k_naive(const float* __restrict__ x, const float* __restrict__ v,
                        const float* __restrict__ W, const float* __restrict__ b,
                        float* __restrict__ out) {
    __shared__ float hv[BLK];
    const int bid = blockIdx.x;
    const int quarter = bid & 3;
    const int g = (bid >> 2) & 7;
    const int row = bid >> 5;
    for (int i = threadIdx.x; i < BLK; i += 256)
        hv[i] = tanhf(v[(size_t)row * TOTAL + g * BLK + i]);
    __syncthreads();
    const int o = quarter * 256 + threadIdx.x;
    const float* wrow = W + ((size_t)g * BLK + o) * BLK;
    float s = 0.f;
    for (int i = 0; i < BLK; ++i) s += hv[i] * wrow[i];
    const size_t oi = (size_t)row * TOTAL + (size_t)((g + 1) & 7) * BLK + o;
    out[oi] = x[oi] + b[g * BLK + o] + s;
}

// ---------- launch ----------

extern "C" void kernel_launch(void* const* d_in, const int* in_sizes, int n_in,
                              void* d_out, int out_size, void* d_ws, size_t ws_size,
                              hipStream_t stream) {
    const float* x = (const float*)d_in[0];
    const float* v = (const float*)d_in[1];
    const float* W = (const float*)d_in[2];
    const float* b = (const float*)d_in[3];
    float* out = (float*)d_out;

    const size_t needH = (size_t)BATCH * TOTAL * sizeof(unsigned short);      // 64 MB
    const size_t needW = (size_t)KGRP * BLK * BLK * sizeof(unsigned short);   // 16 MB

    if (ws_size >= needH + needW) {
        unsigned short* H  = (unsigned short*)d_ws;
        unsigned short* Wb = (unsigned short*)((char*)d_ws + needH);
        k_prep<<<2560, 256, 0, stream>>>((const float4*)v, (ushort4*)H,
                                         (const float4*)W, (ushort4*)Wb);
        k_gemm<<<512, 1024, 0, stream>>>(H, Wb, x, b, out);
    } else {
        k_naive<<<BATCH * KGRP * 4, 256, 0, stream>>>(x, v, W, b, out);
    }
}